// Round 10
// baseline (224.023 us; speedup 1.0000x reference)
//
#include <hip/hip_runtime.h>
#include <hip/hip_bf16.h>

typedef __bf16 bf16_t;
typedef __bf16 bf16x8 __attribute__((ext_vector_type(8)));
typedef float f32x4 __attribute__((ext_vector_type(4)));
typedef __fp16 f16x2 __attribute__((ext_vector_type(2)));

#define BATCH 4
#define SEQ 4096
#define FIN 33
#define DIM 64
#define LOG2E 1.4426950408889634f
#define NWAVE 16   // waves per WG
#define NTILE 16   // 256 cols per wave / 16 cols per MFMA tile
#define NBLK 4     // row-blocks per persistent WG

__device__ __forceinline__ float dexp2(float x) { return __builtin_amdgcn_exp2f(x); }

// LDS-only barrier: orders ds ops across the WG but does NOT drain vmcnt,
// so global output stores stay in flight across block boundaries.
#define BARRIER_LDS()                                          \
    {                                                          \
        asm volatile("s_waitcnt lgkmcnt(0)" ::: "memory");     \
        __builtin_amdgcn_s_barrier();                          \
        asm volatile("" ::: "memory");                         \
    }

// ---------------- Kernel 1: q/k affine projections (fp32 math, bf16 store) ----------------
__global__ __launch_bounds__(256) void qk_proj_kernel(
    const float* __restrict__ x, const float* __restrict__ Wq,
    const float* __restrict__ bq, const float* __restrict__ Wk,
    const float* __restrict__ bk,
    bf16_t* __restrict__ qout, bf16_t* __restrict__ kout)
{
    __shared__ float sWq[FIN * DIM];
    __shared__ float sWk[FIN * DIM];
    __shared__ float sb[2 * DIM];
    const int t = threadIdx.x;
    for (int i = t; i < FIN * DIM; i += 256) { sWq[i] = Wq[i]; sWk[i] = Wk[i]; }
    if (t < DIM) { sb[t] = bq[t]; sb[DIM + t] = bk[t]; }
    __syncthreads();

    const int row = blockIdx.x * 4 + (t >> 6);   // [0, 16384)
    const int d   = t & 63;
    const float* xr = x + (size_t)row * FIN;
    float qacc = sb[d], kacc = sb[DIM + d];
#pragma unroll
    for (int f = 0; f < FIN; ++f) {
        const float xv = xr[f];
        qacc += xv * sWq[f * DIM + d];
        kacc += xv * sWk[f * DIM + d];
    }
    qout[(size_t)row * DIM + d] = (bf16_t)qacc;
    kout[(size_t)row * DIM + d] = (bf16_t)kacc;
}

// ---------------- Kernel 2: persistent fused QK^T + row-max softmax ----------------
// 256 WGs (1/CU), 1024 thr (16 waves), each WG owns 4 consecutive 16-row blocks
// of one batch. ~90 KB static LDS caps occupancy at 1 WG/CU so the register
// allocator budgets 128 VGPR (4 waves/EU) -> the 32-reg fp16 score file stays
// in registers. Store pass of block i is fused per-tile into the sweep of
// block i+1 (register lifetime handoff); LDS-only barriers keep stores in
// flight across blocks.

__device__ __forceinline__ f32x4 mm2(bf16x8 a0, bf16x8 a1, bf16x8 b0, bf16x8 b1)
{
    f32x4 acc = {0.f, 0.f, 0.f, 0.f};
    acc = __builtin_amdgcn_mfma_f32_16x16x32_bf16(a0, b0, acc, 0, 0, 0);
    acc = __builtin_amdgcn_mfma_f32_16x16x32_bf16(a1, b1, acc, 0, 0, 0);
    return acc;
}

#define LD(ct, h) (*reinterpret_cast<const bf16x8*>(kw + (size_t)(ct) * 16 * DIM + (h) * 32))

__global__ __launch_bounds__(1024, 4) void attn_kernel(
    const bf16_t* __restrict__ qg, const bf16_t* __restrict__ kg,
    float* __restrict__ out)
{
    // XCD-contiguous swizzle: XCD x gets logical wgids [x*32, x*32+32)
    // -> each XCD touches only one batch's k (2 MB fits its 4 MB L2).
    const int wgid = ((blockIdx.x & 7) << 5) | (blockIdx.x >> 3);
    const int blk0 = wgid * NBLK;      // first global row-block, 0..1023
    const int b    = blk0 >> 8;        // batch, same for all 4 blocks
    const int t    = threadIdx.x;
    const int w    = t >> 6;           // wave 0..15
    const int l    = t & 63;
    const int lr   = l & 15;           // A-row / B-col lane index
    const int kg4  = l >> 4;           // D rows kg4*4 .. +3
    const int col0 = w << 8;           // 256 cols per wave

    // k pointer: constant across all 4 blocks (same batch)
    const bf16_t* kw = kg + ((size_t)b * SEQ + col0 + lr) * DIM + kg4 * 8;

    __shared__ float redM[NWAVE][16];
    __shared__ float redZ[NWAVE][16];
    // Occupancy pin: forces 1 WG/CU (LDS > 80 KB) => 128-VGPR budget.
    __shared__ char lds_pad[90112];
    if (blockIdx.x == 0x7fffffffu) ((volatile char*)lds_pad)[0] = (char)t;

    f16x2 s[NTILE][2];                 // packed scores / exp values
    float cM[4], invZ[4];

#define REDUCE_M(vmax)                                                          \
    {                                                                           \
        _Pragma("unroll")                                                       \
        for (int m = 1; m < 16; m <<= 1) {                                      \
            _Pragma("unroll")                                                   \
            for (int j = 0; j < 4; ++j)                                         \
                vmax[j] = fmaxf(vmax[j], __shfl_xor(vmax[j], m, 64));           \
        }                                                                       \
        if (lr == 0) {                                                          \
            _Pragma("unroll")                                                   \
            for (int j = 0; j < 4; ++j) redM[w][kg4 * 4 + j] = vmax[j];         \
        }                                                                       \
        BARRIER_LDS();                                                          \
        _Pragma("unroll")                                                       \
        for (int j = 0; j < 4; ++j) {                                           \
            const int r = kg4 * 4 + j;                                          \
            float mm = redM[0][r];                                              \
            _Pragma("unroll")                                                   \
            for (int ww = 1; ww < NWAVE; ++ww) mm = fmaxf(mm, redM[ww][r]);     \
            cM[j] = LOG2E / mm;                                                 \
        }                                                                       \
    }

#define PASS_B()                                                                \
    {                                                                           \
        float vsum[4] = {0.f, 0.f, 0.f, 0.f};                                   \
        _Pragma("unroll")                                                       \
        for (int ct = 0; ct < NTILE; ++ct) {                                    \
            _Pragma("unroll")                                                   \
            for (int h = 0; h < 2; ++h) {                                       \
                const float e0 = dexp2(fmaf((float)s[ct][h][0], cM[2*h+0], -LOG2E)); \
                const float e1 = dexp2(fmaf((float)s[ct][h][1], cM[2*h+1], -LOG2E)); \
                vsum[2*h+0] += e0;                                              \
                vsum[2*h+1] += e1;                                              \
                s[ct][h] = __builtin_amdgcn_cvt_pkrtz(e0, e1);                  \
            }                                                                   \
        }                                                                       \
        _Pragma("unroll")                                                       \
        for (int m = 1; m < 16; m <<= 1) {                                      \
            _Pragma("unroll")                                                   \
            for (int j = 0; j < 4; ++j) vsum[j] += __shfl_xor(vsum[j], m, 64);  \
        }                                                                       \
        if (lr == 0) {                                                          \
            _Pragma("unroll")                                                   \
            for (int j = 0; j < 4; ++j) redZ[w][kg4 * 4 + j] = vsum[j];         \
        }                                                                       \
        BARRIER_LDS();                                                          \
        _Pragma("unroll")                                                       \
        for (int j = 0; j < 4; ++j) {                                           \
            const int r = kg4 * 4 + j;                                          \
            float z = redZ[0][r];                                               \
            _Pragma("unroll")                                                   \
            for (int ww = 1; ww < NWAVE; ++ww) z += redZ[ww][r];                \
            invZ[j] = 1.0f / z;                                                 \
        }                                                                       \
    }

    // ---------- prologue: sweep + reductions for block 0 ----------
    {
        const bf16_t* qb = qg + (size_t)(blk0 * 16) * DIM;
        const bf16x8 a0 = *reinterpret_cast<const bf16x8*>(qb + lr * DIM + kg4 * 8);
        const bf16x8 a1 = *reinterpret_cast<const bf16x8*>(qb + lr * DIM + 32 + kg4 * 8);
        float vmax[4] = {-3.4e38f, -3.4e38f, -3.4e38f, -3.4e38f};
        bf16x8 p0a = LD(0, 0), p0b = LD(0, 1);
        bf16x8 p1a = LD(1, 0), p1b = LD(1, 1);
#pragma unroll
        for (int ct = 0; ct < NTILE; ct += 2) {
            f32x4 acc0 = mm2(a0, a1, p0a, p0b);
            if (ct + 2 < NTILE) { p0a = LD(ct + 2, 0); p0b = LD(ct + 2, 1); }
#pragma unroll
            for (int j = 0; j < 4; ++j) vmax[j] = fmaxf(vmax[j], acc0[j]);
            s[ct][0] = __builtin_amdgcn_cvt_pkrtz(acc0[0], acc0[1]);
            s[ct][1] = __builtin_amdgcn_cvt_pkrtz(acc0[2], acc0[3]);

            f32x4 acc1 = mm2(a0, a1, p1a, p1b);
            if (ct + 3 < NTILE) { p1a = LD(ct + 3, 0); p1b = LD(ct + 3, 1); }
#pragma unroll
            for (int j = 0; j < 4; ++j) vmax[j] = fmaxf(vmax[j], acc1[j]);
            s[ct + 1][0] = __builtin_amdgcn_cvt_pkrtz(acc1[0], acc1[1]);
            s[ct + 1][1] = __builtin_amdgcn_cvt_pkrtz(acc1[2], acc1[3]);
        }
        REDUCE_M(vmax);
        PASS_B();
    }

    // ---------- main loop: store block i fused with sweep of block i+1 ----------
#pragma unroll 1
    for (int i = 0; i < NBLK - 1; ++i) {
        const int blk = blk0 + i;
        float* orow = out + ((size_t)(blk * 16 + kg4 * 4)) * SEQ + col0 + lr;
        const bf16_t* qb = qg + (size_t)((blk + 1) * 16) * DIM;
        const bf16x8 a0 = *reinterpret_cast<const bf16x8*>(qb + lr * DIM + kg4 * 8);
        const bf16x8 a1 = *reinterpret_cast<const bf16x8*>(qb + lr * DIM + 32 + kg4 * 8);
        float vmax[4] = {-3.4e38f, -3.4e38f, -3.4e38f, -3.4e38f};
        bf16x8 p0a = LD(0, 0), p0b = LD(0, 1);
        bf16x8 p1a = LD(1, 0), p1b = LD(1, 1);
#pragma unroll
        for (int ct = 0; ct < NTILE; ct += 2) {
            // tile ct: compute next block's tile, store old, overwrite s[ct]
            f32x4 acc0 = mm2(a0, a1, p0a, p0b);
            if (ct + 2 < NTILE) { p0a = LD(ct + 2, 0); p0b = LD(ct + 2, 1); }
            orow[(size_t)0 * SEQ + ct * 16] = (float)s[ct][0][0] * invZ[0];
            orow[(size_t)1 * SEQ + ct * 16] = (float)s[ct][0][1] * invZ[1];
            orow[(size_t)2 * SEQ + ct * 16] = (float)s[ct][1][0] * invZ[2];
            orow[(size_t)3 * SEQ + ct * 16] = (float)s[ct][1][1] * invZ[3];
#pragma unroll
            for (int j = 0; j < 4; ++j) vmax[j] = fmaxf(vmax[j], acc0[j]);
            s[ct][0] = __builtin_amdgcn_cvt_pkrtz(acc0[0], acc0[1]);
            s[ct][1] = __builtin_amdgcn_cvt_pkrtz(acc0[2], acc0[3]);

            // tile ct+1
            f32x4 acc1 = mm2(a0, a1, p1a, p1b);
            if (ct + 3 < NTILE) { p1a = LD(ct + 3, 0); p1b = LD(ct + 3, 1); }
            orow[(size_t)0 * SEQ + (ct + 1) * 16] = (float)s[ct + 1][0][0] * invZ[0];
            orow[(size_t)1 * SEQ + (ct + 1) * 16] = (float)s[ct + 1][0][1] * invZ[1];
            orow[(size_t)2 * SEQ + (ct + 1) * 16] = (float)s[ct + 1][1][0] * invZ[2];
            orow[(size_t)3 * SEQ + (ct + 1) * 16] = (float)s[ct + 1][1][1] * invZ[3];
#pragma unroll
            for (int j = 0; j < 4; ++j) vmax[j] = fmaxf(vmax[j], acc1[j]);
            s[ct + 1][0] = __builtin_amdgcn_cvt_pkrtz(acc1[0], acc1[1]);
            s[ct + 1][1] = __builtin_amdgcn_cvt_pkrtz(acc1[2], acc1[3]);
        }
        REDUCE_M(vmax);
        PASS_B();
    }

    // ---------- epilogue: plain store pass for the last block ----------
    {
        float* orow = out + ((size_t)((blk0 + NBLK - 1) * 16 + kg4 * 4)) * SEQ + col0 + lr;
#pragma unroll
        for (int ct = 0; ct < NTILE; ++ct) {
            orow[(size_t)0 * SEQ + ct * 16] = (float)s[ct][0][0] * invZ[0];
            orow[(size_t)1 * SEQ + ct * 16] = (float)s[ct][0][1] * invZ[1];
            orow[(size_t)2 * SEQ + ct * 16] = (float)s[ct][1][0] * invZ[2];
            orow[(size_t)3 * SEQ + ct * 16] = (float)s[ct][1][1] * invZ[3];
        }
    }
}

extern "C" void kernel_launch(void* const* d_in, const int* in_sizes, int n_in,
                              void* d_out, int out_size, void* d_ws, size_t ws_size,
                              hipStream_t stream)
{
    const float* x  = (const float*)d_in[0];
    const float* Wq = (const float*)d_in[1];
    const float* bq = (const float*)d_in[2];
    const float* Wk = (const float*)d_in[3];
    const float* bk = (const float*)d_in[4];
    float* out = (float*)d_out;

    bf16_t* qws = (bf16_t*)d_ws;
    bf16_t* kws = qws + (size_t)BATCH * SEQ * DIM;

    qk_proj_kernel<<<(BATCH * SEQ) / 4, 256, 0, stream>>>(x, Wq, bq, Wk, bk, qws, kws);
    attn_kernel<<<256, 1024, 0, stream>>>(qws, kws, out);
}

// Round 11
// 170.064 us; speedup vs baseline: 1.3173x; 1.3173x over previous
//
#include <hip/hip_runtime.h>
#include <hip/hip_bf16.h>

typedef __bf16 bf16_t;
typedef __bf16 bf16x8 __attribute__((ext_vector_type(8)));
typedef float f32x4 __attribute__((ext_vector_type(4)));
typedef __fp16 f16x2 __attribute__((ext_vector_type(2)));

#define BATCH 4
#define SEQ 4096
#define FIN 33
#define DIM 64
#define LOG2E 1.4426950408889634f
#define NWAVE 16   // waves per WG
#define NTILE 16   // 256 cols per wave / 16 cols per MFMA tile
#define NBLK 4     // row-blocks per persistent WG

__device__ __forceinline__ float dexp2(float x) { return __builtin_amdgcn_exp2f(x); }
__device__ __forceinline__ unsigned pk(float a, float b)
{ return __builtin_bit_cast(unsigned, __builtin_amdgcn_cvt_pkrtz(a, b)); }
__device__ __forceinline__ f16x2 uph(unsigned u)
{ return __builtin_bit_cast(f16x2, u); }

// LDS-only barrier: orders LDS ops across the WG but does NOT drain vmcnt,
// so global output stores stay in flight across block boundaries.
#define BARRIER_LDS()                                          \
    {                                                          \
        asm volatile("s_waitcnt lgkmcnt(0)" ::: "memory");     \
        __builtin_amdgcn_s_barrier();                          \
        asm volatile("" ::: "memory");                         \
    }

// ---------------- Kernel 1: q/k affine projections (fp32 math, bf16 store) ----------------
__global__ __launch_bounds__(256) void qk_proj_kernel(
    const float* __restrict__ x, const float* __restrict__ Wq,
    const float* __restrict__ bq, const float* __restrict__ Wk,
    const float* __restrict__ bk,
    bf16_t* __restrict__ qout, bf16_t* __restrict__ kout)
{
    __shared__ float sWq[FIN * DIM];
    __shared__ float sWk[FIN * DIM];
    __shared__ float sb[2 * DIM];
    const int t = threadIdx.x;
    for (int i = t; i < FIN * DIM; i += 256) { sWq[i] = Wq[i]; sWk[i] = Wk[i]; }
    if (t < DIM) { sb[t] = bq[t]; sb[DIM + t] = bk[t]; }
    __syncthreads();

    const int row = blockIdx.x * 4 + (t >> 6);   // [0, 16384)
    const int d   = t & 63;
    const float* xr = x + (size_t)row * FIN;
    float qacc = sb[d], kacc = sb[DIM + d];
#pragma unroll
    for (int f = 0; f < FIN; ++f) {
        const float xv = xr[f];
        qacc += xv * sWq[f * DIM + d];
        kacc += xv * sWk[f * DIM + d];
    }
    qout[(size_t)row * DIM + d] = (bf16_t)qacc;
    kout[(size_t)row * DIM + d] = (bf16_t)kacc;
}

// ---------------- Kernel 2: persistent fused QK^T + row-max softmax ----------------
// 256 WGs (1/CU), 1024 thr (16 waves), each WG owns 4 consecutive 16-row blocks
// of one batch. Scores live in LDS (128 KB; each wave's 16x256 slice private),
// so per-lane VGPR pressure is ~50 and the allocator cannot spill the scores.
// Store pass of block i is fused per-tile into the sweep of block i+1
// (LDS slot handoff: ds_read old e, global store, ds_write new score).
// lgkm-only barriers keep output stores draining across block boundaries.

__device__ __forceinline__ f32x4 mm2(bf16x8 a0, bf16x8 a1, bf16x8 b0, bf16x8 b1)
{
    f32x4 acc = {0.f, 0.f, 0.f, 0.f};
    acc = __builtin_amdgcn_mfma_f32_16x16x32_bf16(a0, b0, acc, 0, 0, 0);
    acc = __builtin_amdgcn_mfma_f32_16x16x32_bf16(a1, b1, acc, 0, 0, 0);
    return acc;
}

#define LD(ct, h) (*reinterpret_cast<const bf16x8*>(kw + (size_t)(ct) * 16 * DIM + (h) * 32))

__global__ __launch_bounds__(1024, 4) void attn_kernel(
    const bf16_t* __restrict__ qg, const bf16_t* __restrict__ kg,
    float* __restrict__ out)
{
    // XCD-contiguous swizzle: XCD x gets logical wgids [x*32, x*32+32)
    // -> each XCD touches only one batch's k (2 MB fits its 4 MB L2).
    const int wgid = ((blockIdx.x & 7) << 5) | (blockIdx.x >> 3);
    const int blk0 = wgid * NBLK;      // first global row-block, 0..1023
    const int b    = blk0 >> 8;        // batch, same for all 4 blocks
    const int t    = threadIdx.x;
    const int w    = t >> 6;           // wave 0..15
    const int l    = t & 63;
    const int lr   = l & 15;           // A-row / B-col lane index
    const int kg4  = l >> 4;           // D rows kg4*4 .. +3
    const int col0 = w << 8;           // 256 cols per wave

    // k pointer: constant across all 4 blocks (same batch)
    const bf16_t* kw = kg + ((size_t)b * SEQ + col0 + lr) * DIM + kg4 * 8;

    // Score store: sS[wave][kg4][col] (uint2 = 4 fp16 rows). Wave-private slice.
    __shared__ uint2 sS[NWAVE][4][256];
    __shared__ float redM[NWAVE][16];
    __shared__ float redZ[NWAVE][16];

    uint2* const sp = &sS[w][kg4][lr];   // + ct*16 per tile
    float cM[4], invZ[4];

#define REDUCE_M(vmax)                                                          \
    {                                                                           \
        _Pragma("unroll")                                                       \
        for (int m = 1; m < 16; m <<= 1) {                                      \
            _Pragma("unroll")                                                   \
            for (int j = 0; j < 4; ++j)                                         \
                vmax[j] = fmaxf(vmax[j], __shfl_xor(vmax[j], m, 64));           \
        }                                                                       \
        if (lr == 0) {                                                          \
            _Pragma("unroll")                                                   \
            for (int j = 0; j < 4; ++j) redM[w][kg4 * 4 + j] = vmax[j];         \
        }                                                                       \
        BARRIER_LDS();                                                          \
        _Pragma("unroll")                                                       \
        for (int j = 0; j < 4; ++j) {                                           \
            const int r = kg4 * 4 + j;                                          \
            float mm = redM[0][r];                                              \
            _Pragma("unroll")                                                   \
            for (int ww = 1; ww < NWAVE; ++ww) mm = fmaxf(mm, redM[ww][r]);     \
            cM[j] = LOG2E / mm;                                                 \
        }                                                                       \
    }

    // exp pass: read scores from LDS, write e back, reduce Z
#define PASS_B()                                                                \
    {                                                                           \
        float vsum[4] = {0.f, 0.f, 0.f, 0.f};                                   \
        _Pragma("unroll")                                                       \
        for (int ct = 0; ct < NTILE; ++ct) {                                    \
            uint2 u = sp[ct * 16];                                              \
            const f16x2 lo = uph(u.x), hi = uph(u.y);                           \
            const float e0 = dexp2(fmaf((float)lo[0], cM[0], -LOG2E));          \
            const float e1 = dexp2(fmaf((float)lo[1], cM[1], -LOG2E));          \
            const float e2 = dexp2(fmaf((float)hi[0], cM[2], -LOG2E));          \
            const float e3 = dexp2(fmaf((float)hi[1], cM[3], -LOG2E));          \
            vsum[0] += e0; vsum[1] += e1; vsum[2] += e2; vsum[3] += e3;         \
            u.x = pk(e0, e1); u.y = pk(e2, e3);                                 \
            sp[ct * 16] = u;                                                    \
        }                                                                       \
        _Pragma("unroll")                                                       \
        for (int m = 1; m < 16; m <<= 1) {                                      \
            _Pragma("unroll")                                                   \
            for (int j = 0; j < 4; ++j) vsum[j] += __shfl_xor(vsum[j], m, 64);  \
        }                                                                       \
        if (lr == 0) {                                                          \
            _Pragma("unroll")                                                   \
            for (int j = 0; j < 4; ++j) redZ[w][kg4 * 4 + j] = vsum[j];         \
        }                                                                       \
        BARRIER_LDS();                                                          \
        _Pragma("unroll")                                                       \
        for (int j = 0; j < 4; ++j) {                                           \
            const int r = kg4 * 4 + j;                                          \
            float z = redZ[0][r];                                               \
            _Pragma("unroll")                                                   \
            for (int ww = 1; ww < NWAVE; ++ww) z += redZ[ww][r];                \
            invZ[j] = 1.0f / z;                                                 \
        }                                                                       \
    }

    // ---------- prologue: sweep + reductions for block 0 ----------
    {
        const bf16_t* qb = qg + (size_t)(blk0 * 16) * DIM;
        const bf16x8 a0 = *reinterpret_cast<const bf16x8*>(qb + lr * DIM + kg4 * 8);
        const bf16x8 a1 = *reinterpret_cast<const bf16x8*>(qb + lr * DIM + 32 + kg4 * 8);
        float vmax[4] = {-3.4e38f, -3.4e38f, -3.4e38f, -3.4e38f};
        bf16x8 p0a = LD(0, 0), p0b = LD(0, 1);
        bf16x8 p1a = LD(1, 0), p1b = LD(1, 1);
#pragma unroll
        for (int ct = 0; ct < NTILE; ct += 2) {
            f32x4 acc0 = mm2(a0, a1, p0a, p0b);
            if (ct + 2 < NTILE) { p0a = LD(ct + 2, 0); p0b = LD(ct + 2, 1); }
#pragma unroll
            for (int j = 0; j < 4; ++j) vmax[j] = fmaxf(vmax[j], acc0[j]);
            sp[ct * 16] = make_uint2(pk(acc0[0], acc0[1]), pk(acc0[2], acc0[3]));

            f32x4 acc1 = mm2(a0, a1, p1a, p1b);
            if (ct + 3 < NTILE) { p1a = LD(ct + 3, 0); p1b = LD(ct + 3, 1); }
#pragma unroll
            for (int j = 0; j < 4; ++j) vmax[j] = fmaxf(vmax[j], acc1[j]);
            sp[(ct + 1) * 16] = make_uint2(pk(acc1[0], acc1[1]), pk(acc1[2], acc1[3]));
        }
        REDUCE_M(vmax);
        PASS_B();
    }

    // ---------- main loop: store block i fused with sweep of block i+1 ----------
#pragma unroll 1
    for (int i = 0; i < NBLK - 1; ++i) {
        const int blk = blk0 + i;
        float* orow = out + ((size_t)(blk * 16 + kg4 * 4)) * SEQ + col0 + lr;
        const bf16_t* qb = qg + (size_t)((blk + 1) * 16) * DIM;
        const bf16x8 a0 = *reinterpret_cast<const bf16x8*>(qb + lr * DIM + kg4 * 8);
        const bf16x8 a1 = *reinterpret_cast<const bf16x8*>(qb + lr * DIM + 32 + kg4 * 8);
        float vmax[4] = {-3.4e38f, -3.4e38f, -3.4e38f, -3.4e38f};
        bf16x8 p0a = LD(0, 0), p0b = LD(0, 1);
        bf16x8 p1a = LD(1, 0), p1b = LD(1, 1);
#pragma unroll
        for (int ct = 0; ct < NTILE; ct += 2) {
            // tile ct: MFMA next block's tile; drain old e from LDS to global;
            // overwrite LDS slot with the new score tile.
            f32x4 acc0 = mm2(a0, a1, p0a, p0b);
            if (ct + 2 < NTILE) { p0a = LD(ct + 2, 0); p0b = LD(ct + 2, 1); }
            {
                const uint2 u = sp[ct * 16];
                const f16x2 lo = uph(u.x), hi = uph(u.y);
                orow[(size_t)0 * SEQ + ct * 16] = (float)lo[0] * invZ[0];
                orow[(size_t)1 * SEQ + ct * 16] = (float)lo[1] * invZ[1];
                orow[(size_t)2 * SEQ + ct * 16] = (float)hi[0] * invZ[2];
                orow[(size_t)3 * SEQ + ct * 16] = (float)hi[1] * invZ[3];
            }
#pragma unroll
            for (int j = 0; j < 4; ++j) vmax[j] = fmaxf(vmax[j], acc0[j]);
            sp[ct * 16] = make_uint2(pk(acc0[0], acc0[1]), pk(acc0[2], acc0[3]));

            // tile ct+1
            f32x4 acc1 = mm2(a0, a1, p1a, p1b);
            if (ct + 3 < NTILE) { p1a = LD(ct + 3, 0); p1b = LD(ct + 3, 1); }
            {
                const uint2 u = sp[(ct + 1) * 16];
                const f16x2 lo = uph(u.x), hi = uph(u.y);
                orow[(size_t)0 * SEQ + (ct + 1) * 16] = (float)lo[0] * invZ[0];
                orow[(size_t)1 * SEQ + (ct + 1) * 16] = (float)lo[1] * invZ[1];
                orow[(size_t)2 * SEQ + (ct + 1) * 16] = (float)hi[0] * invZ[2];
                orow[(size_t)3 * SEQ + (ct + 1) * 16] = (float)hi[1] * invZ[3];
            }
#pragma unroll
            for (int j = 0; j < 4; ++j) vmax[j] = fmaxf(vmax[j], acc1[j]);
            sp[(ct + 1) * 16] = make_uint2(pk(acc1[0], acc1[1]), pk(acc1[2], acc1[3]));
        }
        REDUCE_M(vmax);
        PASS_B();
    }

    // ---------- epilogue: plain store pass for the last block ----------
    {
        float* orow = out + ((size_t)((blk0 + NBLK - 1) * 16 + kg4 * 4)) * SEQ + col0 + lr;
#pragma unroll
        for (int ct = 0; ct < NTILE; ++ct) {
            const uint2 u = sp[ct * 16];
            const f16x2 lo = uph(u.x), hi = uph(u.y);
            orow[(size_t)0 * SEQ + ct * 16] = (float)lo[0] * invZ[0];
            orow[(size_t)1 * SEQ + ct * 16] = (float)lo[1] * invZ[1];
            orow[(size_t)2 * SEQ + ct * 16] = (float)hi[0] * invZ[2];
            orow[(size_t)3 * SEQ + ct * 16] = (float)hi[1] * invZ[3];
        }
    }
}

extern "C" void kernel_launch(void* const* d_in, const int* in_sizes, int n_in,
                              void* d_out, int out_size, void* d_ws, size_t ws_size,
                              hipStream_t stream)
{
    const float* x  = (const float*)d_in[0];
    const float* Wq = (const float*)d_in[1];
    const float* bq = (const float*)d_in[2];
    const float* Wk = (const float*)d_in[3];
    const float* bk = (const float*)d_in[4];
    float* out = (float*)d_out;

    bf16_t* qws = (bf16_t*)d_ws;
    bf16_t* kws = qws + (size_t)BATCH * SEQ * DIM;

    qk_proj_kernel<<<(BATCH * SEQ) / 4, 256, 0, stream>>>(x, Wq, bq, Wk, bk, qws, kws);
    attn_kernel<<<256, 1024, 0, stream>>>(qws, kws, out);
}

// Round 12
// 140.567 us; speedup vs baseline: 1.5937x; 1.2098x over previous
//
#include <hip/hip_runtime.h>
#include <hip/hip_bf16.h>

typedef __bf16 bf16_t;
typedef __bf16 bf16x8 __attribute__((ext_vector_type(8)));
typedef float f32x4 __attribute__((ext_vector_type(4)));
typedef __fp16 f16x2 __attribute__((ext_vector_type(2)));

#define BATCH 4
#define SEQ 4096
#define FIN 33
#define DIM 64
#define LOG2E 1.4426950408889634f
#define NWAVE 16   // waves per WG
#define NTILE 16   // 256 cols per wave / 16 cols per MFMA tile
#define NBLK 4     // row-blocks per persistent WG

__device__ __forceinline__ float dexp2(float x) { return __builtin_amdgcn_exp2f(x); }
__device__ __forceinline__ unsigned pk(float a, float b)
{ return __builtin_bit_cast(unsigned, __builtin_amdgcn_cvt_pkrtz(a, b)); }
__device__ __forceinline__ f16x2 uph(unsigned u)
{ return __builtin_bit_cast(f16x2, u); }
__device__ __forceinline__ float f16lo(unsigned u)
{ return (float)uph(u)[0]; }

// LDS-only barrier: orders LDS ops across the WG but does NOT drain vmcnt.
#define BARRIER_LDS()                                          \
    {                                                          \
        asm volatile("s_waitcnt lgkmcnt(0)" ::: "memory");     \
        __builtin_amdgcn_s_barrier();                          \
        asm volatile("" ::: "memory");                         \
    }

// ---------------- Kernel 1: q/k affine projections ----------------
__global__ __launch_bounds__(256) void qk_proj_kernel(
    const float* __restrict__ x, const float* __restrict__ Wq,
    const float* __restrict__ bq, const float* __restrict__ Wk,
    const float* __restrict__ bk,
    bf16_t* __restrict__ qout, bf16_t* __restrict__ kout)
{
    __shared__ float sWq[FIN * DIM];
    __shared__ float sWk[FIN * DIM];
    __shared__ float sb[2 * DIM];
    const int t = threadIdx.x;
    for (int i = t; i < FIN * DIM; i += 256) { sWq[i] = Wq[i]; sWk[i] = Wk[i]; }
    if (t < DIM) { sb[t] = bq[t]; sb[DIM + t] = bk[t]; }
    __syncthreads();

    const int row = blockIdx.x * 4 + (t >> 6);
    const int d   = t & 63;
    const float* xr = x + (size_t)row * FIN;
    float qacc = sb[d], kacc = sb[DIM + d];
#pragma unroll
    for (int f = 0; f < FIN; ++f) {
        const float xv = xr[f];
        qacc += xv * sWq[f * DIM + d];
        kacc += xv * sWk[f * DIM + d];
    }
    qout[(size_t)row * DIM + d] = (bf16_t)qacc;
    kout[(size_t)row * DIM + d] = (bf16_t)kacc;
}

// ---------------- Kernel 2: persistent fused QK^T + row-max softmax ----------------
// 256 WGs (1/CU), 16 waves. Scores in LDS (128 KB, wave-private slices).
// Phases per block: sweep (pure vmem-load+MFMA+ds_write) -> M-reduce ->
// exp pass (pure VALU/LDS) -> Z-reduce -> store pass (pure ds_read+store,
// 128B full-line dwordx4 stores). Next sweep's prefetch loads are issued
// BEFORE the store pass so MFMA waits never drain stores (vmcnt FIFO order).

__device__ __forceinline__ f32x4 mm2(bf16x8 a0, bf16x8 a1, bf16x8 b0, bf16x8 b1)
{
    f32x4 acc = {0.f, 0.f, 0.f, 0.f};
    acc = __builtin_amdgcn_mfma_f32_16x16x32_bf16(a0, b0, acc, 0, 0, 0);
    acc = __builtin_amdgcn_mfma_f32_16x16x32_bf16(a1, b1, acc, 0, 0, 0);
    return acc;
}

#define LD(ct, h) (*reinterpret_cast<const bf16x8*>(kw + (size_t)(ct) * 16 * DIM + (h) * 32))

__global__ __launch_bounds__(1024, 4) void attn_kernel(
    const bf16_t* __restrict__ qg, const bf16_t* __restrict__ kg,
    float* __restrict__ out)
{
    const int wgid = ((blockIdx.x & 7) << 5) | (blockIdx.x >> 3);
    const int blk0 = wgid * NBLK;      // first row-block, 0..1023
    const int b    = blk0 >> 8;        // batch
    const int t    = threadIdx.x;
    const int w    = t >> 6;           // wave 0..15
    const int l    = t & 63;
    const int lr   = l & 15;
    const int kg4  = l >> 4;
    const int col0 = w << 8;           // 256 cols per wave

    const bf16_t* kw = kg + ((size_t)b * SEQ + col0 + lr) * DIM + kg4 * 8;

    __shared__ uint2 sS[NWAVE][4][256];   // scores/e: [wave][row-group][col]
    __shared__ float redM[NWAVE][16];
    __shared__ float redZ[NWAVE][16];

    uint2* const sp = &sS[w][kg4][lr];
    float cM[4];

#define REDUCE_M(vmax)                                                          \
    {                                                                           \
        _Pragma("unroll")                                                       \
        for (int m = 1; m < 16; m <<= 1) {                                      \
            _Pragma("unroll")                                                   \
            for (int j = 0; j < 4; ++j)                                         \
                vmax[j] = fmaxf(vmax[j], __shfl_xor(vmax[j], m, 64));           \
        }                                                                       \
        if (lr == 0) {                                                          \
            _Pragma("unroll")                                                   \
            for (int j = 0; j < 4; ++j) redM[w][kg4 * 4 + j] = vmax[j];         \
        }                                                                       \
        BARRIER_LDS();                                                          \
        _Pragma("unroll")                                                       \
        for (int j = 0; j < 4; ++j) {                                           \
            const int r = kg4 * 4 + j;                                          \
            float mm = redM[0][r];                                              \
            _Pragma("unroll")                                                   \
            for (int ww = 1; ww < NWAVE; ++ww) mm = fmaxf(mm, redM[ww][r]);     \
            cM[j] = LOG2E / mm;                                                 \
        }                                                                       \
    }

    // exp pass: read scores from LDS, write e back, reduce Z into redZ.
#define PASS_B()                                                                \
    {                                                                           \
        float vsum[4] = {0.f, 0.f, 0.f, 0.f};                                   \
        _Pragma("unroll")                                                       \
        for (int ct = 0; ct < NTILE; ++ct) {                                    \
            uint2 u = sp[ct * 16];                                              \
            const f16x2 lo = uph(u.x), hi = uph(u.y);                           \
            const float e0 = dexp2(fmaf((float)lo[0], cM[0], -LOG2E));          \
            const float e1 = dexp2(fmaf((float)lo[1], cM[1], -LOG2E));          \
            const float e2 = dexp2(fmaf((float)hi[0], cM[2], -LOG2E));          \
            const float e3 = dexp2(fmaf((float)hi[1], cM[3], -LOG2E));          \
            vsum[0] += e0; vsum[1] += e1; vsum[2] += e2; vsum[3] += e3;         \
            u.x = pk(e0, e1); u.y = pk(e2, e3);                                 \
            sp[ct * 16] = u;                                                    \
        }                                                                       \
        _Pragma("unroll")                                                       \
        for (int m = 1; m < 16; m <<= 1) {                                      \
            _Pragma("unroll")                                                   \
            for (int j = 0; j < 4; ++j) vsum[j] += __shfl_xor(vsum[j], m, 64);  \
        }                                                                       \
        if (lr == 0) {                                                          \
            _Pragma("unroll")                                                   \
            for (int j = 0; j < 4; ++j) redZ[w][kg4 * 4 + j] = vsum[j];         \
        }                                                                       \
        BARRIER_LDS();                                                          \
    }

    // sweep body for block at q-base qb (pure: loads + MFMA + ds_write)
#define SWEEP_BODY(a0, a1, p0a, p0b, p1a, p1b, vmax)                            \
    {                                                                           \
        _Pragma("unroll")                                                       \
        for (int ct = 0; ct < NTILE; ct += 2) {                                 \
            f32x4 acc0 = mm2(a0, a1, p0a, p0b);                                 \
            if (ct + 2 < NTILE) { p0a = LD(ct + 2, 0); p0b = LD(ct + 2, 1); }   \
            _Pragma("unroll")                                                   \
            for (int j = 0; j < 4; ++j) vmax[j] = fmaxf(vmax[j], acc0[j]);      \
            sp[ct * 16] = make_uint2(pk(acc0[0], acc0[1]), pk(acc0[2], acc0[3])); \
            f32x4 acc1 = mm2(a0, a1, p1a, p1b);                                 \
            if (ct + 3 < NTILE) { p1a = LD(ct + 3, 0); p1b = LD(ct + 3, 1); }   \
            _Pragma("unroll")                                                   \
            for (int j = 0; j < 4; ++j) vmax[j] = fmaxf(vmax[j], acc1[j]);      \
            sp[(ct + 1) * 16] = make_uint2(pk(acc1[0], acc1[1]), pk(acc1[2], acc1[3])); \
        }                                                                       \
    }

    // store pass: full 128B-line stores. lane -> row sr=l>>3 (and sr+8),
    // cols (l&7)*4 + 32*it. Reads e from LDS, scales by invZ from redZ.
#define STORE_PASS(blk)                                                         \
    {                                                                           \
        const int  sr  = l >> 3;                                                \
        const int  cl  = (l & 7) * 4;                                           \
        const unsigned hsh = (unsigned)((sr & 1) * 16);                         \
        const bool hiw = (sr & 2) != 0;                                         \
        const int  g0  = sr >> 2;                                               \
        float z0 = 0.f, z1 = 0.f;                                               \
        _Pragma("unroll")                                                       \
        for (int ww = 0; ww < NWAVE; ++ww) {                                    \
            z0 += redZ[ww][sr]; z1 += redZ[ww][sr + 8];                         \
        }                                                                       \
        const float iz0 = 1.0f / z0, iz1 = 1.0f / z1;                           \
        float* ob0 = out + ((size_t)((blk) * 16 + sr)) * SEQ + col0;            \
        float* ob1 = ob0 + (size_t)8 * SEQ;                                     \
        _Pragma("unroll")                                                       \
        for (int it = 0; it < 8; ++it) {                                        \
            const int c = it * 32 + cl;                                         \
            const uint4 A0 = *reinterpret_cast<const uint4*>(&sS[w][g0][c]);    \
            const uint4 B0 = *reinterpret_cast<const uint4*>(&sS[w][g0][c + 2]);\
            const uint4 A1 = *reinterpret_cast<const uint4*>(&sS[w][g0 + 2][c]);\
            const uint4 B1 = *reinterpret_cast<const uint4*>(&sS[w][g0 + 2][c + 2]);\
            f32x4 v0, v1;                                                       \
            v0[0] = f16lo((hiw ? A0.y : A0.x) >> hsh);                          \
            v0[1] = f16lo((hiw ? A0.w : A0.z) >> hsh);                          \
            v0[2] = f16lo((hiw ? B0.y : B0.x) >> hsh);                          \
            v0[3] = f16lo((hiw ? B0.w : B0.z) >> hsh);                          \
            v1[0] = f16lo((hiw ? A1.y : A1.x) >> hsh);                          \
            v1[1] = f16lo((hiw ? A1.w : A1.z) >> hsh);                          \
            v1[2] = f16lo((hiw ? B1.y : B1.x) >> hsh);                          \
            v1[3] = f16lo((hiw ? B1.w : B1.z) >> hsh);                          \
            *reinterpret_cast<f32x4*>(ob0 + c) = v0 * iz0;                      \
            *reinterpret_cast<f32x4*>(ob1 + c) = v1 * iz1;                      \
        }                                                                       \
    }

    // ---------- prologue: block 0 sweep + reductions ----------
    {
        const bf16_t* qb = qg + (size_t)(blk0 * 16) * DIM;
        bf16x8 a0 = *reinterpret_cast<const bf16x8*>(qb + lr * DIM + kg4 * 8);
        bf16x8 a1 = *reinterpret_cast<const bf16x8*>(qb + lr * DIM + 32 + kg4 * 8);
        bf16x8 p0a = LD(0, 0), p0b = LD(0, 1);
        bf16x8 p1a = LD(1, 0), p1b = LD(1, 1);
        float vmax[4] = {-3.4e38f, -3.4e38f, -3.4e38f, -3.4e38f};
        SWEEP_BODY(a0, a1, p0a, p0b, p1a, p1b, vmax);
        REDUCE_M(vmax);
        PASS_B();
    }

    // ---------- main loop ----------
#pragma unroll 1
    for (int i = 0; i < NBLK; ++i) {
        const int blk = blk0 + i;
        if (i + 1 < NBLK) {
            // prefetch next block's q/k BEFORE the store pass: these loads are
            // older than the stores in the vmcnt FIFO, so the first MFMAs of
            // the next sweep never wait on store completion.
            const bf16_t* qb = qg + (size_t)((blk + 1) * 16) * DIM;
            bf16x8 a0 = *reinterpret_cast<const bf16x8*>(qb + lr * DIM + kg4 * 8);
            bf16x8 a1 = *reinterpret_cast<const bf16x8*>(qb + lr * DIM + 32 + kg4 * 8);
            bf16x8 p0a = LD(0, 0), p0b = LD(0, 1);
            bf16x8 p1a = LD(1, 0), p1b = LD(1, 1);
            __builtin_amdgcn_sched_barrier(0);   // keep prefetch ahead of stores

            STORE_PASS(blk);

            float vmax[4] = {-3.4e38f, -3.4e38f, -3.4e38f, -3.4e38f};
            SWEEP_BODY(a0, a1, p0a, p0b, p1a, p1b, vmax);
            REDUCE_M(vmax);
            PASS_B();
        } else {
            STORE_PASS(blk);
        }
    }
}

extern "C" void kernel_launch(void* const* d_in, const int* in_sizes, int n_in,
                              void* d_out, int out_size, void* d_ws, size_t ws_size,
                              hipStream_t stream)
{
    const float* x  = (const float*)d_in[0];
    const float* Wq = (const float*)d_in[1];
    const float* bq = (const float*)d_in[2];
    const float* Wk = (const float*)d_in[3];
    const float* bk = (const float*)d_in[4];
    float* out = (float*)d_out;

    bf16_t* qws = (bf16_t*)d_ws;
    bf16_t* kws = qws + (size_t)BATCH * SEQ * DIM;

    qk_proj_kernel<<<(BATCH * SEQ) / 4, 256, 0, stream>>>(x, Wq, bq, Wk, bk, qws, kws);
    attn_kernel<<<256, 1024, 0, stream>>>(qws, kws, out);
}